// Round 2
// baseline (342.483 us; speedup 1.0000x reference)
//
#include <hip/hip_runtime.h>
#include <hip/hip_bf16.h>
#include <math.h>

#define NTOK 1024
#define DPROJ 1024
#define PSTRIDE 1376
#define HEADS 20003
#define LOG2E 1.4426950408889634f
#define LN2   0.6931471805599453f
#define WSCALE (4.0f * LOG2E)
#define PSCALE 0.25f

#if __has_builtin(__builtin_amdgcn_exp2f)
#define EXP2(x) __builtin_amdgcn_exp2f(x)
#else
#define EXP2(x) exp2f(x)
#endif

#define MFMA8(a, b, c) __builtin_amdgcn_mfma_f32_16x16x32_fp8_fp8(a, b, c, 0, 0, 0)

typedef __attribute__((ext_vector_type(8))) short bf16x8;
typedef __attribute__((ext_vector_type(4))) float f32x4;
typedef long long i64;

__device__ __forceinline__ short f2bf(float f) {
    unsigned u = __float_as_uint(f);
    u += 0x7fffu + ((u >> 16) & 1u);
    return (short)(u >> 16);
}
__device__ __forceinline__ unsigned pk4fp8(float a, float b, float c, float d) {
    unsigned v = __builtin_amdgcn_cvt_pk_fp8_f32(a, b, 0, false);
    v = __builtin_amdgcn_cvt_pk_fp8_f32(c, d, v, true);
    return v;
}
__device__ __forceinline__ unsigned char fp8_1(float a) {
    return (unsigned char)(__builtin_amdgcn_cvt_pk_fp8_f32(a, a, 0, false) & 0xff);
}
// w row fragment -> fp8 with WSCALE
__device__ __forceinline__ i64 wfrag(const float* wp) {
    float4 x = *(const float4*)(wp);
    float4 y = *(const float4*)(wp + 4);
    unsigned lo = pk4fp8(x.x * WSCALE, x.y * WSCALE, x.z * WSCALE, x.w * WSCALE);
    unsigned hi = pk4fp8(y.x * WSCALE, y.y * WSCALE, y.z * WSCALE, y.w * WSCALE);
    return (i64)(((unsigned long long)hi << 32) | lo);
}

// slab counts (one slab = 1024-token partial sums)
#define NB0 157          // head slabs (157 vocab-blocks of 128 rows)
#define NB0G 314         // head grid: token-split x2
#define NB1T 157         // t1: VT=2 -> 128 rows/block
#define NB2T 313         // t2: VT=8 -> 512 rows/block
#define NB3T 133         // t3: VT=8 -> 512 rows/block
#define NBT (NB1T + NB2T + NB3T)   // 603
#define NSLAB (NB0 + NBT)          // 760

// padded eb sizes (rows covered by the lse grids)
#define EB0N 20096    // 157*128
#define EB1N 20096    // 157*128
#define EB2N 160256   // 313*512
#define EB3N 68096    // 133*512
#define EBTOT (EB0N + EB1N + EB2N + EB3N)  // 268544 = 1049*256

// ================= prep (+ absorbed memsets + eb tables) ========================
__global__ __launch_bounds__(256) void prep(const float* __restrict__ hidden,
                                            const float* __restrict__ p0,
                                            const float* __restrict__ p1,
                                            const float* __restrict__ p2,
                                            const float* __restrict__ p3,
                                            const float* __restrict__ b0,
                                            const float* __restrict__ b1,
                                            const float* __restrict__ b2,
                                            const float* __restrict__ b3,
                                            short* __restrict__ hbP,
                                            short* __restrict__ pTbP0,
                                            short* __restrict__ pTbP1,
                                            short* __restrict__ pTbP2,
                                            short* __restrict__ pTbP3,
                                            float* __restrict__ sums,
                                            unsigned char* __restrict__ pk3,
                                            float* __restrict__ eb0,
                                            float* __restrict__ eb1,
                                            float* __restrict__ eb2,
                                            float* __restrict__ eb3) {
    __shared__ float tile[64][65];
    int bid = blockIdx.x, tid = threadIdx.x;
    if (bid >= 418) {                       // eb tables: exp2(bias*log2e), 0 on pad rows
        int g = (bid - 418) * 256 + tid;
        if (g < EB0N) {
            eb0[g] = (g < HEADS) ? exp2f(b0[g] * LOG2E) : 0.f;
        } else if (g < EB0N + EB1N) {
            int i = g - EB0N;
            eb1[i] = (i < 20000) ? exp2f(b1[i] * LOG2E) : 0.f;
        } else if (g < EB0N + EB1N + EB2N) {
            int i = g - EB0N - EB1N;
            eb2[i] = (i < 160000) ? exp2f(b2[i] * LOG2E) : 0.f;
        } else if (g < EBTOT) {
            int i = g - EB0N - EB1N - EB2N;
            eb3[i] = (i < 67735) ? exp2f(b3[i] * LOG2E) : 0.f;
        }
        return;
    }
    if (bid == 416) {                       // zero sums (4*1024 floats) for reduce_part atomics
        float4 z = {0.f, 0.f, 0.f, 0.f};
        #pragma unroll
        for (int i = 0; i < 4; ++i) *((float4*)sums + i * 256 + tid) = z;
        return;
    }
    if (bid == 417) {                       // zero pk3 (32768 B, for k-pad)
        int4 z = {0, 0, 0, 0};
        #pragma unroll
        for (int i = 0; i < 8; ++i) *((int4*)pk3 + i * 256 + tid) = z;
        return;
    }
    if (bid < 64) {
        int tt = bid;
        #pragma unroll
        for (int q = 0; q < 8; ++q) {
            int fi = q * 256 + tid;
            int l = fi & 63;
            int row = tt * 16 + (l & 15);
            int kb = (fi >> 6) * 32 + (l >> 4) * 8;
            const float* hp = hidden + row * 1024 + kb;
            float4 x = *(const float4*)hp;
            float4 y = *(const float4*)(hp + 4);
            bf16x8 o;
            o[0]=f2bf(x.x); o[1]=f2bf(x.y); o[2]=f2bf(x.z); o[3]=f2bf(x.w);
            o[4]=f2bf(y.x); o[5]=f2bf(y.y); o[6]=f2bf(y.z); o[7]=f2bf(y.w);
            *(bf16x8*)(hbP + (size_t)tt * 16384 + fi * 8) = o;
        }
        return;
    }
    int lb = bid - 64;
    const float* p; short* dst; int d, kt, jb;
    if (lb < 256)      { p = p0; dst = pTbP0; d = 1024; kt = lb >> 4; jb = lb & 15; }
    else if (lb < 320) { lb -= 256; p = p1; dst = pTbP1; d = 256; kt = lb >> 2; jb = lb & 3; }
    else if (lb < 336) { lb -= 320; p = p2; dst = pTbP2; d = 64;  kt = lb; jb = 0; }
    else               { lb -= 336; p = p3; dst = pTbP3; d = 16;  kt = lb; jb = 0; }
    int k0 = kt * 64, j0 = jb * 64;
    int tx = tid & 63, ty = tid >> 6;
    #pragma unroll
    for (int rr = 0; rr < 16; ++rr) {
        int k = k0 + ty * 16 + rr;
        int j = j0 + tx;
        if (j < d) tile[ty * 16 + rr][tx] = p[k * d + j];
    }
    __syncthreads();
    int ch = tid >> 5;
    int jtl = ch >> 1, ksl = ch & 1;
    int jt = jb * 4 + jtl;
    if (jt * 16 < d) {
        #pragma unroll
        for (int li = 0; li < 2; ++li) {
            int l = (tid & 31) + li * 32;
            int jl = jtl * 16 + (l & 15);
            int kl = ksl * 32 + (l >> 4) * 8;
            bf16x8 o;
            #pragma unroll
            for (int e = 0; e < 8; ++e) o[e] = f2bf(tile[kl + e][jl]);
            *(bf16x8*)(dst + ((size_t)jt * 32 + kt * 2 + ksl) * 512 + l * 8) = o;
        }
    }
}

// ================= proj: bf16 MFMA; projf fp32 exact; pk fp8 scaled =============
__global__ __launch_bounds__(256) void proj(const short* __restrict__ hbP,
                                            const short* __restrict__ pTbP0,
                                            const short* __restrict__ pTbP1,
                                            const short* __restrict__ pTbP2,
                                            const short* __restrict__ pTbP3,
                                            float* __restrict__ projf,
                                            unsigned char* __restrict__ pk0,
                                            unsigned char* __restrict__ pk1,
                                            unsigned char* __restrict__ pk2,
                                            unsigned char* __restrict__ pk3) {
    __shared__ float spackf[16][72];
    __shared__ unsigned char sp8[1024];
    int tt = blockIdx.x, jbG = blockIdx.y, tid = threadIdx.x;
    const short* pB; unsigned char* pkc; int d, KSp, coloff, jb;
    if (jbG < 16)      { pB = pTbP0; pkc = pk0; d = 1024; KSp = 32; coloff = 0;    jb = jbG; }
    else if (jbG < 20) { pB = pTbP1; pkc = pk1; d = 256;  KSp = 8;  coloff = 1024; jb = jbG - 16; }
    else if (jbG == 20){ pB = pTbP2; pkc = pk2; d = 64;   KSp = 2;  coloff = 1280; jb = 0; }
    else               { pB = pTbP3; pkc = pk3; d = 16;   KSp = 1;  coloff = 1344; jb = 0; }
    int w = tid >> 6, lane = tid & 63;
    int l16 = lane & 15, quad = lane >> 4;
    int jt = jb * 4 + w;
    if (jt * 16 < d) {
        const short* ap = hbP + ((size_t)tt * 32) * 512 + lane * 8;
        const short* bp = pB  + ((size_t)jt * 32) * 512 + lane * 8;
        f32x4 x0 = {0,0,0,0}, x1 = {0,0,0,0};
        #pragma unroll
        for (int ks = 0; ks < 16; ++ks) {
            bf16x8 a0 = *(const bf16x8*)(ap + ks * 512);
            bf16x8 b0 = *(const bf16x8*)(bp + ks * 512);
            bf16x8 a1 = *(const bf16x8*)(ap + (ks + 16) * 512);
            bf16x8 b1 = *(const bf16x8*)(bp + (ks + 16) * 512);
            x0 = __builtin_amdgcn_mfma_f32_16x16x32_bf16(a0, b0, x0, 0, 0, 0);
            x1 = __builtin_amdgcn_mfma_f32_16x16x32_bf16(a1, b1, x1, 0, 0, 0);
        }
        f32x4 acc = x0 + x1;
        int kk = w * 16 + l16;
        #pragma unroll
        for (int r = 0; r < 4; ++r) {
            int tok = quad * 4 + r;
            spackf[tok][kk] = acc[r];
            sp8[(kk >> 5) * 512 + ((kk & 31) >> 3) * 128 + tok * 8 + (kk & 7)] = fp8_1(acc[r] * PSCALE);
        }
    }
    __syncthreads();
    int j0g = jb * 64;
    int dcols = min(64, d - j0g);
    {
        int row = tid >> 4, cb = (tid & 15) * 4;
        if (cb < dcols) {
            float4 v = *(const float4*)&spackf[row][cb];
            *(float4*)&projf[(tt * 16 + row) * PSTRIDE + coloff + j0g + cb] = v;
        }
    }
    {
        int nbytes = 16 * dcols;
        if (tid * 4 < nbytes) {
            unsigned char* gdst = pkc + ((size_t)tt * KSp + (j0g >> 5)) * 512;
            *(unsigned*)(gdst + tid * 4) = *(const unsigned*)(sp8 + tid * 4);
        }
    }
}

// ================= lse =========================================================
__device__ __forceinline__ void stage16k(const unsigned char* g, unsigned char* l,
                                         int wave, int lane) {
    const unsigned char* gs = g + wave * 4096 + lane * 16;
    unsigned char* ls = l + wave * 4096;
    #pragma unroll
    for (int i = 0; i < 4; ++i)
        __builtin_amdgcn_global_load_lds(
            (const __attribute__((address_space(1))) unsigned*)(gs + i * 1024),
            (__attribute__((address_space(3))) unsigned*)(ls + i * 1024), 16, 0, 0);
}

// head kernel: VT=2, KS=32, LDS double-buffered B, token-split x2.
// __launch_bounds__(256,1): areg[2][32]=128 VGPRs must stay resident (no spill).
__global__ __launch_bounds__(256, 1) void lse_head_k(const float* __restrict__ w,
                                                     const float* __restrict__ eb,
                                                     const unsigned char* __restrict__ pk,
                                                     float* __restrict__ part) {
    __shared__ unsigned char sbuf[2][16384];
    __shared__ float bsum[512];
    int bid = blockIdx.x;
    int bh = bid >> 1, th = bid & 1;      // vocab-block, token-half
    int tid = threadIdx.x;
    int wave = tid >> 6, lane = tid & 63;
    int quad = lane >> 4, l16 = lane & 15;
    int v0 = bh * 128 + wave * 32;

    for (int i = tid; i < 512; i += 256) bsum[i] = 0.f;

    i64 areg[2][32];
    float ee[2][4];
    #pragma unroll
    for (int vt = 0; vt < 2; ++vt) {
        int va = v0 + vt * 16 + l16;
        #pragma unroll
        for (int ks = 0; ks < 32; ++ks)
            areg[vt][ks] = (va < HEADS) ? wfrag(w + (long)va * 1024 + ks * 32 + quad * 8) : 0;
        #pragma unroll
        for (int r = 0; r < 4; ++r)
            ee[vt][r] = eb[v0 + vt * 16 + quad * 4 + r];   // padded: 0 beyond HEADS
    }

    const unsigned char* pkt = pk + (size_t)th * 32 * 16384;
    stage16k(pkt, sbuf[0], wave, lane);
    __syncthreads();
    for (int t = 0; t < 32; ++t) {
        if (t < 31) stage16k(pkt + (size_t)(t + 1) * 16384, sbuf[(t + 1) & 1], wave, lane);
        const unsigned char* sb = sbuf[t & 1];
        f32x4 x0 = {0,0,0,0}, x1 = x0, x2 = x0, x3 = x0;
        __builtin_amdgcn_s_setprio(1);
        #pragma unroll
        for (int j = 0; j < 16; ++j) {
            i64 b0 = *(const i64*)(sb + j * 512 + lane * 8);
            i64 b1 = *(const i64*)(sb + (j + 16) * 512 + lane * 8);
            x0 = MFMA8(areg[0][j],      b0, x0);
            x1 = MFMA8(areg[0][j + 16], b1, x1);
            x2 = MFMA8(areg[1][j],      b0, x2);
            x3 = MFMA8(areg[1][j + 16], b1, x3);
        }
        __builtin_amdgcn_s_setprio(0);
        f32x4 a0 = x0 + x1, a1 = x2 + x3;
        float e0 = EXP2(a0[0]) * ee[0][0], e1 = EXP2(a0[1]) * ee[0][1];
        e0 += EXP2(a0[2]) * ee[0][2];  e1 += EXP2(a0[3]) * ee[0][3];
        e0 += EXP2(a1[0]) * ee[1][0];  e1 += EXP2(a1[1]) * ee[1][1];
        e0 += EXP2(a1[2]) * ee[1][2];  e1 += EXP2(a1[3]) * ee[1][3];
        float e = e0 + e1;
        e += __shfl_xor(e, 16, 64);
        e += __shfl_xor(e, 32, 64);
        if (lane < 16) atomicAdd(&bsum[t * 16 + lane], e);
        __syncthreads();
    }
    // write this block's 512-token half of slab bh (the two halves are disjoint)
    if (tid < 128)
        ((float4*)(part + (size_t)bh * NTOK + th * 512))[tid] = ((const float4*)bsum)[tid];
}

// tails: global-direct B with register double-buffer
template <int KS, int VT>
__device__ __forceinline__ void lse_tail(const float* __restrict__ w,
                                         const float* __restrict__ eb,
                                         const unsigned char* __restrict__ pk,
                                         float* __restrict__ part,
                                         int V, int D, int bid, float* bsum) {
    int tid = threadIdx.x;
    int wave = tid >> 6, lane = tid & 63;
    int quad = lane >> 4, l16 = lane & 15;
    int v0 = bid * (64 * VT) + wave * (16 * VT);

    for (int i = tid; i < NTOK; i += 256) bsum[i] = 0.f;
    __syncthreads();

    i64 areg[VT][KS];
    float ee[VT][4];
    #pragma unroll
    for (int vt = 0; vt < VT; ++vt) {
        int va = v0 + vt * 16 + l16;
        #pragma unroll
        for (int ks = 0; ks < KS; ++ks) {
            int k = ks * 32 + quad * 8;
            areg[vt][ks] = (va < V && k < D) ? wfrag(w + (long)va * D + k) : 0;
        }
        #pragma unroll
        for (int r = 0; r < 4; ++r)
            ee[vt][r] = eb[v0 + vt * 16 + quad * 4 + r];   // padded: 0 beyond V
    }

    const i64* base = (const i64*)pk;
    i64 bn[KS];
    #pragma unroll
    for (int k = 0; k < KS; ++k) bn[k] = base[k * 64 + lane];
    for (int tt = 0; tt < 64; ++tt) {
        i64 bc[KS];
        #pragma unroll
        for (int k = 0; k < KS; ++k) bc[k] = bn[k];
        if (tt < 63) {
            const i64* nb = base + (size_t)(tt + 1) * KS * 64;
            #pragma unroll
            for (int k = 0; k < KS; ++k) bn[k] = nb[k * 64 + lane];
        }
        // MFMA cluster first (setprio), then VALU epilogue
        f32x4 accs[VT];
        __builtin_amdgcn_s_setprio(1);
        #pragma unroll
        for (int vt = 0; vt < VT; ++vt) {
            if constexpr (KS >= 4) {
                f32x4 y0 = {0,0,0,0}, y1 = {0,0,0,0};
                #pragma unroll
                for (int j = 0; j < KS / 2; ++j) {
                    y0 = MFMA8(areg[vt][j],          bc[j],          y0);
                    y1 = MFMA8(areg[vt][KS/2 + j],   bc[KS/2 + j],   y1);
                }
                accs[vt] = y0 + y1;
            } else if constexpr (KS == 2) {
                f32x4 y = {0,0,0,0};
                y = MFMA8(areg[vt][0], bc[0], y);
                y = MFMA8(areg[vt][1], bc[1], y);
                accs[vt] = y;
            } else {
                f32x4 y = {0,0,0,0};
                accs[vt] = MFMA8(areg[vt][0], bc[0], y);
            }
        }
        __builtin_amdgcn_s_setprio(0);
        float e0 = 0.f, e1 = 0.f;
        #pragma unroll
        for (int vt = 0; vt < VT; ++vt) {
            e0 += EXP2(accs[vt][0]) * ee[vt][0];
            e1 += EXP2(accs[vt][1]) * ee[vt][1];
            e0 += EXP2(accs[vt][2]) * ee[vt][2];
            e1 += EXP2(accs[vt][3]) * ee[vt][3];
        }
        float e = e0 + e1;
        e += __shfl_xor(e, 16, 64);
        e += __shfl_xor(e, 32, 64);
        if (lane < 16) atomicAdd(&bsum[tt * 16 + lane], e);
    }
    __syncthreads();
    *((float4*)part + tid) = *((const float4*)bsum + tid);
}

__global__ __launch_bounds__(256, 4) void lse_tails(const float* __restrict__ w1, const float* __restrict__ eb1,
                                                    const float* __restrict__ w2, const float* __restrict__ eb2,
                                                    const float* __restrict__ w3, const float* __restrict__ eb3,
                                                    const unsigned char* __restrict__ pk1,
                                                    const unsigned char* __restrict__ pk2,
                                                    const unsigned char* __restrict__ pk3,
                                                    float* __restrict__ part) {
    __shared__ float bsum[NTOK];
    int bid = blockIdx.x;
    float* slab = part + (size_t)(NB0 + bid) * NTOK;
    if (bid < NB1T) {
        lse_tail<8, 2>(w1, eb1, pk1, slab, 20000,  256, bid, bsum);
    } else if (bid < NB1T + NB2T) {
        lse_tail<2, 8>(w2, eb2, pk2, slab, 160000, 64,  bid - NB1T, bsum);
    } else {
        lse_tail<1, 8>(w3, eb3, pk3, slab, 67735,  16,  bid - NB1T - NB2T, bsum);
    }
}

// ================= reduce partial slabs -> sums ================================
__global__ __launch_bounds__(256) void reduce_part(const float* __restrict__ part,
                                                   float* __restrict__ sums) {
    // grid: 4 clusters * 4 token-quarters * 8 slab-slices = 128 blocks
    int bid = blockIdx.x;
    int c = bid >> 5, rem = bid & 31, q = rem >> 3, sl = rem & 7;
    const int off[4] = {0, NB0, NB0 + NB1T, NB0 + NB1T + NB2T};
    const int cnt[4] = {NB0, NB1T, NB2T, NB3T};
    int tok = q * 256 + threadIdx.x;
    const float* p = part + (size_t)off[c] * NTOK + tok;
    int n = cnt[c];
    float s0 = 0.f, s1 = 0.f, s2 = 0.f, s3 = 0.f;
    int b = sl;
    for (; b + 24 < n; b += 32) {
        s0 += p[(size_t)b * NTOK];
        s1 += p[(size_t)(b + 8) * NTOK];
        s2 += p[(size_t)(b + 16) * NTOK];
        s3 += p[(size_t)(b + 24) * NTOK];
    }
    for (; b < n; b += 8) s0 += p[(size_t)b * NTOK];
    float s = (s0 + s1) + (s2 + s3);
    atomicAdd(&sums[c * NTOK + tok], s);   // 8 atomics/address, sums pre-zeroed in prep
}

// ================= finalize ====================================================
__global__ __launch_bounds__(256) void finalize(const int* __restrict__ target,
                                                const float* __restrict__ projf,
                                                const float* __restrict__ sums,
                                                const float* __restrict__ w0, const float* __restrict__ b0,
                                                const float* __restrict__ w1, const float* __restrict__ b1,
                                                const float* __restrict__ w2, const float* __restrict__ b2,
                                                const float* __restrict__ w3, const float* __restrict__ b3,
                                                float* __restrict__ out) {
    int wave = threadIdx.x >> 6, lane = threadIdx.x & 63;
    int row = blockIdx.x * 4 + wave;
    int t = target[row];
    int c = (t < 20000) ? 0 : (t < 40000) ? 1 : (t < 200000) ? 2 : 3;
    int col0 = (c == 0) ? t : (HEADS - c);
    const float* pr = projf + row * PSTRIDE;

    float s = 0.f;
    for (int k = lane; k < DPROJ; k += 64) s += pr[k] * w0[col0 * DPROJ + k];
    #pragma unroll
    for (int off = 32; off; off >>= 1) s += __shfl_xor(s, off, 64);
    float hl = s + b0[col0];
    float lse0 = __log2f(sums[row]) * LN2;

    float res;
    if (c == 0) {
        res = lse0 - hl;
    } else {
        const float* wc; const float* bc; int d, coloff, l;
        if (c == 1)      { wc = w1; bc = b1; d = 256; coloff = 1024; l = 20000; }
        else if (c == 2) { wc = w2; bc = b2; d = 64;  coloff = 1280; l = 40000; }
        else             { wc = w3; bc = b3; d = 16;  coloff = 1344; l = 200000; }
        int tc = t - l;
        float s2 = 0.f;
        for (int k = lane; k < d; k += 64) s2 += pr[coloff + k] * wc[tc * d + k];
        #pragma unroll
        for (int off = 32; off; off >>= 1) s2 += __shfl_xor(s2, off, 64);
        float tl = s2 + bc[tc];
        float lsec = __log2f(sums[c * NTOK + row]) * LN2;
        res = lse0 - hl + lsec - tl;
    }
    if (lane == 0) out[row] = res;
}

// ================= workspace layout =============================================
// hbP   (short) @ elem 0          : 1,048,576
// pTbP0 (short) @ elem 1,048,576  : 1,048,576
// pTbP1 (short) @ elem 2,097,152  :   262,144
// pTbP2 (short) @ elem 2,359,296  :    65,536
// pTbP3 (short) @ elem 2,424,832  :    16,384
// projf (float) @ byte 4,882,432  : 1,409,024 floats
// pk0..3 (u8)   @ byte 10,518,528 : 1 MB / 256 KB / 64 KB / 32 KB
// sums  (float) @ byte 11,927,552 : 4096 floats           -> ends 11,943,936
// part  (float) @ byte 11,943,936 : 760*1024 floats (3,112,960 B) -> ends 15,056,896
// eb0   (float) @ byte 15,056,896 : 20096  (80,384 B)
// eb1   (float) @ byte 15,137,280 : 20096  (80,384 B)
// eb2   (float) @ byte 15,217,664 : 160256 (641,024 B)
// eb3   (float) @ byte 15,858,688 : 68096  (272,384 B)    -> ends 16,131,072

extern "C" void kernel_launch(void* const* d_in, const int* in_sizes, int n_in,
                              void* d_out, int out_size, void* d_ws, size_t ws_size,
                              hipStream_t stream) {
    const float* hidden = (const float*)d_in[0];
    const int*   target = (const int*)d_in[1];
    const float* w0 = (const float*)d_in[2];
    const float* b0 = (const float*)d_in[3];
    const float* p0 = (const float*)d_in[4];
    const float* w1 = (const float*)d_in[5];
    const float* b1 = (const float*)d_in[6];
    const float* p1 = (const float*)d_in[7];
    const float* w2 = (const float*)d_in[8];
    const float* b2 = (const float*)d_in[9];
    const float* p2 = (const float*)d_in[10];
    const float* w3 = (const float*)d_in[11];
    const float* b3 = (const float*)d_in[12];
    const float* p3 = (const float*)d_in[13];

    short* base = (short*)d_ws;
    short* hbP   = base;
    short* pTbP0 = base + 1048576;
    short* pTbP1 = base + 2097152;
    short* pTbP2 = base + 2359296;
    short* pTbP3 = base + 2424832;
    float* projf = (float*)((char*)d_ws + 4882432);
    unsigned char* pk0 = (unsigned char*)d_ws + 10518528;
    unsigned char* pk1 = pk0 + 1048576;
    unsigned char* pk2 = pk1 + 262144;
    unsigned char* pk3 = pk2 + 65536;
    float* sums  = (float*)((char*)d_ws + 11927552);
    float* part  = (float*)((char*)d_ws + 11943936);
    float* eb0   = (float*)((char*)d_ws + 15056896);
    float* eb1   = (float*)((char*)d_ws + 15137280);
    float* eb2   = (float*)((char*)d_ws + 15217664);
    float* eb3   = (float*)((char*)d_ws + 15858688);

    prep<<<1467, 256, 0, stream>>>(hidden, p0, p1, p2, p3, b0, b1, b2, b3,
                                   hbP, pTbP0, pTbP1, pTbP2, pTbP3, sums, pk3,
                                   eb0, eb1, eb2, eb3);
    proj<<<dim3(64, 22), 256, 0, stream>>>(hbP, pTbP0, pTbP1, pTbP2, pTbP3,
                                           projf, pk0, pk1, pk2, pk3);
    lse_head_k<<<NB0G, 256, 0, stream>>>(w0, eb0, pk0, part);
    lse_tails<<<NBT, 256, 0, stream>>>(w1, eb1, w2, eb2, w3, eb3,
                                       pk1, pk2, pk3, part);
    reduce_part<<<128, 256, 0, stream>>>(part, sums);
    finalize<<<256, 256, 0, stream>>>(target, projf, sums,
                                      w0, b0, w1, b1, w2, b2, w3, b3, (float*)d_out);
}

// Round 3
// 310.626 us; speedup vs baseline: 1.1026x; 1.1026x over previous
//
#include <hip/hip_runtime.h>
#include <hip/hip_bf16.h>
#include <math.h>

#define NTOK 1024
#define DPROJ 1024
#define PSTRIDE 1376
#define HEADS 20003
#define LOG2E 1.4426950408889634f
#define LN2   0.6931471805599453f
#define WSCALE (4.0f * LOG2E)
#define PSCALE 0.25f

#if __has_builtin(__builtin_amdgcn_exp2f)
#define EXP2(x) __builtin_amdgcn_exp2f(x)
#else
#define EXP2(x) exp2f(x)
#endif

#define MFMA8(a, b, c) __builtin_amdgcn_mfma_f32_16x16x32_fp8_fp8(a, b, c, 0, 0, 0)

typedef __attribute__((ext_vector_type(8))) short bf16x8;
typedef __attribute__((ext_vector_type(4))) float f32x4;
typedef long long i64;
typedef __attribute__((ext_vector_type(2))) long long i64x2;

__device__ __forceinline__ short f2bf(float f) {
    unsigned u = __float_as_uint(f);
    u += 0x7fffu + ((u >> 16) & 1u);
    return (short)(u >> 16);
}
__device__ __forceinline__ unsigned pk4fp8(float a, float b, float c, float d) {
    unsigned v = __builtin_amdgcn_cvt_pk_fp8_f32(a, b, 0, false);
    v = __builtin_amdgcn_cvt_pk_fp8_f32(c, d, v, true);
    return v;
}
__device__ __forceinline__ unsigned char fp8_1(float a) {
    return (unsigned char)(__builtin_amdgcn_cvt_pk_fp8_f32(a, a, 0, false) & 0xff);
}
// w row fragment -> fp8 with WSCALE
__device__ __forceinline__ i64 wfrag(const float* wp) {
    float4 x = *(const float4*)(wp);
    float4 y = *(const float4*)(wp + 4);
    unsigned lo = pk4fp8(x.x * WSCALE, x.y * WSCALE, x.z * WSCALE, x.w * WSCALE);
    unsigned hi = pk4fp8(y.x * WSCALE, y.y * WSCALE, y.z * WSCALE, y.w * WSCALE);
    return (i64)(((unsigned long long)hi << 32) | lo);
}

// block counts for fused lse_all (one slab = 1024-token partials per block)
#define NB0H 313         // head: VT=1, 64 rows/block  (313*64 = 20032 >= 20003)
#define NB1T 157         // t1:   VT=2, 128 rows/block (157*128 = 20096)
#define NB2T 313         // t2:   VT=8, 512 rows/block (313*512 = 160256)
#define NB3T 133         // t3:   VT=8, 512 rows/block (133*512 = 68096)
#define NSLAB (NB0H + NB1T + NB2T + NB3T)   // 916

// padded eb sizes (rows covered by the lse grids)
#define EB0N 20096
#define EB1N 20096
#define EB2N 160256
#define EB3N 68096
#define EBTOT (EB0N + EB1N + EB2N + EB3N)  // 268544 = 1049*256

// ================= prep (+ absorbed memsets + eb tables) ========================
__global__ __launch_bounds__(256) void prep(const float* __restrict__ hidden,
                                            const float* __restrict__ p0,
                                            const float* __restrict__ p1,
                                            const float* __restrict__ p2,
                                            const float* __restrict__ p3,
                                            const float* __restrict__ b0,
                                            const float* __restrict__ b1,
                                            const float* __restrict__ b2,
                                            const float* __restrict__ b3,
                                            short* __restrict__ hbP,
                                            short* __restrict__ pTbP0,
                                            short* __restrict__ pTbP1,
                                            short* __restrict__ pTbP2,
                                            short* __restrict__ pTbP3,
                                            float* __restrict__ sums,
                                            unsigned char* __restrict__ pk3,
                                            float* __restrict__ eb0,
                                            float* __restrict__ eb1,
                                            float* __restrict__ eb2,
                                            float* __restrict__ eb3) {
    __shared__ float tile[64][65];
    int bid = blockIdx.x, tid = threadIdx.x;
    if (bid >= 418) {                       // eb tables: exp2(bias*log2e), 0 on pad rows
        int g = (bid - 418) * 256 + tid;
        if (g < EB0N) {
            eb0[g] = (g < HEADS) ? exp2f(b0[g] * LOG2E) : 0.f;
        } else if (g < EB0N + EB1N) {
            int i = g - EB0N;
            eb1[i] = (i < 20000) ? exp2f(b1[i] * LOG2E) : 0.f;
        } else if (g < EB0N + EB1N + EB2N) {
            int i = g - EB0N - EB1N;
            eb2[i] = (i < 160000) ? exp2f(b2[i] * LOG2E) : 0.f;
        } else if (g < EBTOT) {
            int i = g - EB0N - EB1N - EB2N;
            eb3[i] = (i < 67735) ? exp2f(b3[i] * LOG2E) : 0.f;
        }
        return;
    }
    if (bid == 416) {                       // zero sums (4*1024 floats) for reduce_part atomics
        float4 z = {0.f, 0.f, 0.f, 0.f};
        #pragma unroll
        for (int i = 0; i < 4; ++i) *((float4*)sums + i * 256 + tid) = z;
        return;
    }
    if (bid == 417) {                       // zero pk3 (32768 B, for k-pad)
        int4 z = {0, 0, 0, 0};
        #pragma unroll
        for (int i = 0; i < 8; ++i) *((int4*)pk3 + i * 256 + tid) = z;
        return;
    }
    if (bid < 64) {
        int tt = bid;
        #pragma unroll
        for (int q = 0; q < 8; ++q) {
            int fi = q * 256 + tid;
            int l = fi & 63;
            int row = tt * 16 + (l & 15);
            int kb = (fi >> 6) * 32 + (l >> 4) * 8;
            const float* hp = hidden + row * 1024 + kb;
            float4 x = *(const float4*)hp;
            float4 y = *(const float4*)(hp + 4);
            bf16x8 o;
            o[0]=f2bf(x.x); o[1]=f2bf(x.y); o[2]=f2bf(x.z); o[3]=f2bf(x.w);
            o[4]=f2bf(y.x); o[5]=f2bf(y.y); o[6]=f2bf(y.z); o[7]=f2bf(y.w);
            *(bf16x8*)(hbP + (size_t)tt * 16384 + fi * 8) = o;
        }
        return;
    }
    int lb = bid - 64;
    const float* p; short* dst; int d, kt, jb;
    if (lb < 256)      { p = p0; dst = pTbP0; d = 1024; kt = lb >> 4; jb = lb & 15; }
    else if (lb < 320) { lb -= 256; p = p1; dst = pTbP1; d = 256; kt = lb >> 2; jb = lb & 3; }
    else if (lb < 336) { lb -= 320; p = p2; dst = pTbP2; d = 64;  kt = lb; jb = 0; }
    else               { lb -= 336; p = p3; dst = pTbP3; d = 16;  kt = lb; jb = 0; }
    int k0 = kt * 64, j0 = jb * 64;
    int tx = tid & 63, ty = tid >> 6;
    #pragma unroll
    for (int rr = 0; rr < 16; ++rr) {
        int k = k0 + ty * 16 + rr;
        int j = j0 + tx;
        if (j < d) tile[ty * 16 + rr][tx] = p[k * d + j];
    }
    __syncthreads();
    int ch = tid >> 5;
    int jtl = ch >> 1, ksl = ch & 1;
    int jt = jb * 4 + jtl;
    if (jt * 16 < d) {
        #pragma unroll
        for (int li = 0; li < 2; ++li) {
            int l = (tid & 31) + li * 32;
            int jl = jtl * 16 + (l & 15);
            int kl = ksl * 32 + (l >> 4) * 8;
            bf16x8 o;
            #pragma unroll
            for (int e = 0; e < 8; ++e) o[e] = f2bf(tile[kl + e][jl]);
            *(bf16x8*)(dst + ((size_t)jt * 32 + kt * 2 + ksl) * 512 + l * 8) = o;
        }
    }
}

// ================= proj: bf16 MFMA; projf fp32 exact; pk fp8 scaled =============
// pk layout (d>16, "paired"): per token-tile tt, per 64-k group ksp:
//   byte = tt*(KSp*512) + ksp*1024 + lane*16 + half*8 + e   (half = (k>>5)&1)
//   -> one 16B read per lane yields the i64 B-frags for ks=2*ksp and 2*ksp+1.
// pk3 (d=16) keeps the old unpaired 512B-slice layout.
__global__ __launch_bounds__(256) void proj(const short* __restrict__ hbP,
                                            const short* __restrict__ pTbP0,
                                            const short* __restrict__ pTbP1,
                                            const short* __restrict__ pTbP2,
                                            const short* __restrict__ pTbP3,
                                            float* __restrict__ projf,
                                            unsigned char* __restrict__ pk0,
                                            unsigned char* __restrict__ pk1,
                                            unsigned char* __restrict__ pk2,
                                            unsigned char* __restrict__ pk3) {
    __shared__ float spackf[16][72];
    __shared__ unsigned char sp8[1024];
    int tt = blockIdx.x, jbG = blockIdx.y, tid = threadIdx.x;
    const short* pB; unsigned char* pkc; int d, KSp, coloff, jb;
    if (jbG < 16)      { pB = pTbP0; pkc = pk0; d = 1024; KSp = 32; coloff = 0;    jb = jbG; }
    else if (jbG < 20) { pB = pTbP1; pkc = pk1; d = 256;  KSp = 8;  coloff = 1024; jb = jbG - 16; }
    else if (jbG == 20){ pB = pTbP2; pkc = pk2; d = 64;   KSp = 2;  coloff = 1280; jb = 0; }
    else               { pB = pTbP3; pkc = pk3; d = 16;   KSp = 1;  coloff = 1344; jb = 0; }
    int w = tid >> 6, lane = tid & 63;
    int l16 = lane & 15, quad = lane >> 4;
    int jt = jb * 4 + w;
    if (jt * 16 < d) {
        const short* ap = hbP + ((size_t)tt * 32) * 512 + lane * 8;
        const short* bp = pB  + ((size_t)jt * 32) * 512 + lane * 8;
        f32x4 x0 = {0,0,0,0}, x1 = {0,0,0,0};
        #pragma unroll
        for (int ks = 0; ks < 16; ++ks) {
            bf16x8 a0 = *(const bf16x8*)(ap + ks * 512);
            bf16x8 b0 = *(const bf16x8*)(bp + ks * 512);
            bf16x8 a1 = *(const bf16x8*)(ap + (ks + 16) * 512);
            bf16x8 b1 = *(const bf16x8*)(bp + (ks + 16) * 512);
            x0 = __builtin_amdgcn_mfma_f32_16x16x32_bf16(a0, b0, x0, 0, 0, 0);
            x1 = __builtin_amdgcn_mfma_f32_16x16x32_bf16(a1, b1, x1, 0, 0, 0);
        }
        f32x4 acc = x0 + x1;
        int kk = w * 16 + l16;
        #pragma unroll
        for (int r = 0; r < 4; ++r) {
            int tok = quad * 4 + r;
            spackf[tok][kk] = acc[r];
            int idx;
            if (d > 16) idx = ((kk & 31) >> 3) * 256 + tok * 16 + (kk >> 5) * 8 + (kk & 7);
            else        idx = ((kk & 31) >> 3) * 128 + tok * 8 + (kk & 7);
            sp8[idx] = fp8_1(acc[r] * PSCALE);
        }
    }
    __syncthreads();
    int j0g = jb * 64;
    int dcols = min(64, d - j0g);
    {
        int row = tid >> 4, cb = (tid & 15) * 4;
        if (cb < dcols) {
            float4 v = *(const float4*)&spackf[row][cb];
            *(float4*)&projf[(tt * 16 + row) * PSTRIDE + coloff + j0g + cb] = v;
        }
    }
    {
        int nbytes = 16 * dcols;
        if (tid * 4 < nbytes) {
            unsigned char* gdst = pkc + ((size_t)tt * KSp + (j0g >> 5)) * 512;
            *(unsigned*)(gdst + tid * 4) = *(const unsigned*)(sp8 + tid * 4);
        }
    }
}

// ================= lse =========================================================
__device__ __forceinline__ void stage16k(const unsigned char* g, unsigned char* l,
                                         int wave, int lane) {
    const unsigned char* gs = g + wave * 4096 + lane * 16;
    unsigned char* ls = l + wave * 4096;
    #pragma unroll
    for (int i = 0; i < 4; ++i)
        __builtin_amdgcn_global_load_lds(
            (const __attribute__((address_space(1))) unsigned*)(gs + i * 1024),
            (__attribute__((address_space(3))) unsigned*)(ls + i * 1024), 16, 0, 0);
}

// head: VT=1 (areg = 32 i64 = 64 VGPR, stays register-resident), paired b128 reads
__device__ __forceinline__ void lse_head(const float* __restrict__ w,
                                         const float* __restrict__ eb,
                                         const unsigned char* __restrict__ pk,
                                         float* __restrict__ part, int bid,
                                         unsigned char (*sbuf)[16384], float* bsum) {
    int tid = threadIdx.x;
    int wave = tid >> 6, lane = tid & 63;
    int quad = lane >> 4, l16 = lane & 15;
    int v0 = bid * 64 + wave * 16;

    for (int i = tid; i < NTOK; i += 256) bsum[i] = 0.f;

    i64 areg[32];
    float ee[4];
    int va = v0 + l16;
    #pragma unroll
    for (int ks = 0; ks < 32; ++ks)
        areg[ks] = (va < HEADS) ? wfrag(w + (long)va * 1024 + ks * 32 + quad * 8) : 0;
    #pragma unroll
    for (int r = 0; r < 4; ++r)
        ee[r] = eb[v0 + quad * 4 + r];   // padded: 0 beyond HEADS

    stage16k(pk, sbuf[0], wave, lane);
    __syncthreads();
    for (int tt = 0; tt < 64; ++tt) {
        if (tt < 63) stage16k(pk + (size_t)(tt + 1) * 16384, sbuf[(tt + 1) & 1], wave, lane);
        const unsigned char* sb = sbuf[tt & 1];
        f32x4 x0 = {0,0,0,0}, x1 = x0;
        __builtin_amdgcn_s_setprio(1);
        #pragma unroll
        for (int p = 0; p < 16; ++p) {
            i64x2 b2 = *(const i64x2*)(sb + p * 1024 + lane * 16);
            x0 = MFMA8(areg[2 * p],     b2[0], x0);
            x1 = MFMA8(areg[2 * p + 1], b2[1], x1);
        }
        __builtin_amdgcn_s_setprio(0);
        f32x4 a = x0 + x1;
        float e0 = EXP2(a[0]) * ee[0] + EXP2(a[2]) * ee[2];
        float e1 = EXP2(a[1]) * ee[1] + EXP2(a[3]) * ee[3];
        float e = e0 + e1;
        e += __shfl_xor(e, 16, 64);
        e += __shfl_xor(e, 32, 64);
        if (lane < 16) atomicAdd(&bsum[tt * 16 + lane], e);
        __syncthreads();
    }
    *((float4*)part + tid) = *((const float4*)bsum + tid);
}

// tails: global-direct B with register double-buffer (paired 16B loads for KS>=2)
template <int KS, int VT>
__device__ __forceinline__ void lse_tail(const float* __restrict__ w,
                                         const float* __restrict__ eb,
                                         const unsigned char* __restrict__ pk,
                                         float* __restrict__ part,
                                         int V, int D, int bid, float* bsum) {
    int tid = threadIdx.x;
    int wave = tid >> 6, lane = tid & 63;
    int quad = lane >> 4, l16 = lane & 15;
    int v0 = bid * (64 * VT) + wave * (16 * VT);

    for (int i = tid; i < NTOK; i += 256) bsum[i] = 0.f;
    __syncthreads();

    i64 areg[VT][KS];
    float ee[VT][4];
    #pragma unroll
    for (int vt = 0; vt < VT; ++vt) {
        int va = v0 + vt * 16 + l16;
        #pragma unroll
        for (int ks = 0; ks < KS; ++ks) {
            int k = ks * 32 + quad * 8;
            areg[vt][ks] = (va < V && k < D) ? wfrag(w + (long)va * D + k) : 0;
        }
        #pragma unroll
        for (int r = 0; r < 4; ++r)
            ee[vt][r] = eb[v0 + vt * 16 + quad * 4 + r];   // padded: 0 beyond V
    }

    if constexpr (KS >= 2) {
        constexpr int KSP = KS / 2;
        i64x2 bn[KSP], bc[KSP];
        #pragma unroll
        for (int p = 0; p < KSP; ++p)
            bn[p] = *(const i64x2*)(pk + p * 1024 + lane * 16);
        for (int tt = 0; tt < 64; ++tt) {
            #pragma unroll
            for (int p = 0; p < KSP; ++p) bc[p] = bn[p];
            if (tt < 63) {
                const unsigned char* nb = pk + (size_t)(tt + 1) * (KS * 512);
                #pragma unroll
                for (int p = 0; p < KSP; ++p)
                    bn[p] = *(const i64x2*)(nb + p * 1024 + lane * 16);
            }
            float e0 = 0.f, e1 = 0.f;
            #pragma unroll
            for (int vt = 0; vt < VT; ++vt) {
                f32x4 y0 = {0,0,0,0}, y1 = {0,0,0,0};
                __builtin_amdgcn_s_setprio(1);
                #pragma unroll
                for (int p = 0; p < KSP; ++p) {
                    y0 = MFMA8(areg[vt][2 * p],     bc[p][0], y0);
                    y1 = MFMA8(areg[vt][2 * p + 1], bc[p][1], y1);
                }
                __builtin_amdgcn_s_setprio(0);
                f32x4 a = y0 + y1;
                e0 += EXP2(a[0]) * ee[vt][0];
                e1 += EXP2(a[1]) * ee[vt][1];
                e0 += EXP2(a[2]) * ee[vt][2];
                e1 += EXP2(a[3]) * ee[vt][3];
            }
            float e = e0 + e1;
            e += __shfl_xor(e, 16, 64);
            e += __shfl_xor(e, 32, 64);
            if (lane < 16) atomicAdd(&bsum[tt * 16 + lane], e);
        }
    } else {
        i64 bn = *(const i64*)(pk + lane * 8);
        for (int tt = 0; tt < 64; ++tt) {
            i64 bc = bn;
            if (tt < 63) bn = *(const i64*)(pk + (size_t)(tt + 1) * 512 + lane * 8);
            float e0 = 0.f, e1 = 0.f;
            #pragma unroll
            for (int vt = 0; vt < VT; ++vt) {
                f32x4 y0 = {0,0,0,0};
                f32x4 a = MFMA8(areg[vt][0], bc, y0);
                e0 += EXP2(a[0]) * ee[vt][0];
                e1 += EXP2(a[1]) * ee[vt][1];
                e0 += EXP2(a[2]) * ee[vt][2];
                e1 += EXP2(a[3]) * ee[vt][3];
            }
            float e = e0 + e1;
            e += __shfl_xor(e, 16, 64);
            e += __shfl_xor(e, 32, 64);
            if (lane < 16) atomicAdd(&bsum[tt * 16 + lane], e);
        }
    }
    __syncthreads();
    *((float4*)part + tid) = *((const float4*)bsum + tid);
}

__global__ __launch_bounds__(256, 2) void lse_all(const float* __restrict__ w0, const float* __restrict__ eb0,
                                                  const float* __restrict__ w1, const float* __restrict__ eb1,
                                                  const float* __restrict__ w2, const float* __restrict__ eb2,
                                                  const float* __restrict__ w3, const float* __restrict__ eb3,
                                                  const unsigned char* __restrict__ pk0,
                                                  const unsigned char* __restrict__ pk1,
                                                  const unsigned char* __restrict__ pk2,
                                                  const unsigned char* __restrict__ pk3,
                                                  float* __restrict__ part) {
    __shared__ unsigned char sbuf[2][16384];
    __shared__ float bsum[NTOK];
    int bid = blockIdx.x;
    float* slab = part + (size_t)bid * NTOK;
    if (bid < NB0H) {
        lse_head(w0, eb0, pk0, slab, bid, sbuf, bsum);
    } else if (bid < NB0H + NB1T) {
        lse_tail<8, 2>(w1, eb1, pk1, slab, 20000,  256, bid - NB0H, bsum);
    } else if (bid < NB0H + NB1T + NB2T) {
        lse_tail<2, 8>(w2, eb2, pk2, slab, 160000, 64,  bid - NB0H - NB1T, bsum);
    } else {
        lse_tail<1, 8>(w3, eb3, pk3, slab, 67735,  16,  bid - NB0H - NB1T - NB2T, bsum);
    }
}

// ================= reduce partial slabs -> sums ================================
__global__ __launch_bounds__(256) void reduce_part(const float* __restrict__ part,
                                                   float* __restrict__ sums) {
    // grid: 4 clusters * 4 token-quarters * 8 slab-slices = 128 blocks
    int bid = blockIdx.x;
    int c = bid >> 5, rem = bid & 31, q = rem >> 3, sl = rem & 7;
    const int off[4] = {0, NB0H, NB0H + NB1T, NB0H + NB1T + NB2T};
    const int cnt[4] = {NB0H, NB1T, NB2T, NB3T};
    int tok = q * 256 + threadIdx.x;
    const float* p = part + (size_t)off[c] * NTOK + tok;
    int n = cnt[c];
    float s0 = 0.f, s1 = 0.f, s2 = 0.f, s3 = 0.f;
    int b = sl;
    for (; b + 24 < n; b += 32) {
        s0 += p[(size_t)b * NTOK];
        s1 += p[(size_t)(b + 8) * NTOK];
        s2 += p[(size_t)(b + 16) * NTOK];
        s3 += p[(size_t)(b + 24) * NTOK];
    }
    for (; b < n; b += 8) s0 += p[(size_t)b * NTOK];
    float s = (s0 + s1) + (s2 + s3);
    atomicAdd(&sums[c * NTOK + tok], s);   // 8 atomics/address, sums pre-zeroed in prep
}

// ================= finalize ====================================================
__global__ __launch_bounds__(256) void finalize(const int* __restrict__ target,
                                                const float* __restrict__ projf,
                                                const float* __restrict__ sums,
                                                const float* __restrict__ w0, const float* __restrict__ b0,
                                                const float* __restrict__ w1, const float* __restrict__ b1,
                                                const float* __restrict__ w2, const float* __restrict__ b2,
                                                const float* __restrict__ w3, const float* __restrict__ b3,
                                                float* __restrict__ out) {
    int wave = threadIdx.x >> 6, lane = threadIdx.x & 63;
    int row = blockIdx.x * 4 + wave;
    int t = target[row];
    int c = (t < 20000) ? 0 : (t < 40000) ? 1 : (t < 200000) ? 2 : 3;
    int col0 = (c == 0) ? t : (HEADS - c);
    const float* pr = projf + row * PSTRIDE;

    float s = 0.f;
    for (int k = lane; k < DPROJ; k += 64) s += pr[k] * w0[col0 * DPROJ + k];
    #pragma unroll
    for (int off = 32; off; off >>= 1) s += __shfl_xor(s, off, 64);
    float hl = s + b0[col0];
    float lse0 = __log2f(sums[row]) * LN2;

    float res;
    if (c == 0) {
        res = lse0 - hl;
    } else {
        const float* wc; const float* bc; int d, coloff, l;
        if (c == 1)      { wc = w1; bc = b1; d = 256; coloff = 1024; l = 20000; }
        else if (c == 2) { wc = w2; bc = b2; d = 64;  coloff = 1280; l = 40000; }
        else             { wc = w3; bc = b3; d = 16;  coloff = 1344; l = 200000; }
        int tc = t - l;
        float s2 = 0.f;
        for (int k = lane; k < d; k += 64) s2 += pr[coloff + k] * wc[tc * d + k];
        #pragma unroll
        for (int off = 32; off; off >>= 1) s2 += __shfl_xor(s2, off, 64);
        float tl = s2 + bc[tc];
        float lsec = __log2f(sums[c * NTOK + row]) * LN2;
        res = lse0 - hl + lsec - tl;
    }
    if (lane == 0) out[row] = res;
}

// ================= workspace layout =============================================
// hbP   (short) @ elem 0          : 1,048,576
// pTbP0 (short) @ elem 1,048,576  : 1,048,576
// pTbP1 (short) @ elem 2,097,152  :   262,144
// pTbP2 (short) @ elem 2,359,296  :    65,536
// pTbP3 (short) @ elem 2,424,832  :    16,384
// projf (float) @ byte 4,882,432  : 1,409,024 floats
// pk0..3 (u8)   @ byte 10,518,528 : 1 MB / 256 KB / 64 KB / 32 KB
// sums  (float) @ byte 11,927,552 : 4096 floats           -> ends 11,943,936
// part  (float) @ byte 11,943,936 : 916*1024 floats (3,751,936 B) -> ends 15,695,872
// eb0   (float) @ byte 15,695,872 : 20096  (80,384 B)
// eb1   (float) @ byte 15,776,256 : 20096  (80,384 B)
// eb2   (float) @ byte 15,856,640 : 160256 (641,024 B)
// eb3   (float) @ byte 16,497,664 : 68096  (272,384 B)    -> ends 16,770,048

extern "C" void kernel_launch(void* const* d_in, const int* in_sizes, int n_in,
                              void* d_out, int out_size, void* d_ws, size_t ws_size,
                              hipStream_t stream) {
    const float* hidden = (const float*)d_in[0];
    const int*   target = (const int*)d_in[1];
    const float* w0 = (const float*)d_in[2];
    const float* b0 = (const float*)d_in[3];
    const float* p0 = (const float*)d_in[4];
    const float* w1 = (const float*)d_in[5];
    const float* b1 = (const float*)d_in[6];
    const float* p1 = (const float*)d_in[7];
    const float* w2 = (const float*)d_in[8];
    const float* b2 = (const float*)d_in[9];
    const float* p2 = (const float*)d_in[10];
    const float* w3 = (const float*)d_in[11];
    const float* b3 = (const float*)d_in[12];
    const float* p3 = (const float*)d_in[13];

    short* base = (short*)d_ws;
    short* hbP   = base;
    short* pTbP0 = base + 1048576;
    short* pTbP1 = base + 2097152;
    short* pTbP2 = base + 2359296;
    short* pTbP3 = base + 2424832;
    float* projf = (float*)((char*)d_ws + 4882432);
    unsigned char* pk0 = (unsigned char*)d_ws + 10518528;
    unsigned char* pk1 = pk0 + 1048576;
    unsigned char* pk2 = pk1 + 262144;
    unsigned char* pk3 = pk2 + 65536;
    float* sums  = (float*)((char*)d_ws + 11927552);
    float* part  = (float*)((char*)d_ws + 11943936);
    float* eb0   = (float*)((char*)d_ws + 15695872);
    float* eb1   = (float*)((char*)d_ws + 15776256);
    float* eb2   = (float*)((char*)d_ws + 15856640);
    float* eb3   = (float*)((char*)d_ws + 16497664);

    prep<<<1467, 256, 0, stream>>>(hidden, p0, p1, p2, p3, b0, b1, b2, b3,
                                   hbP, pTbP0, pTbP1, pTbP2, pTbP3, sums, pk3,
                                   eb0, eb1, eb2, eb3);
    proj<<<dim3(64, 22), 256, 0, stream>>>(hbP, pTbP0, pTbP1, pTbP2, pTbP3,
                                           projf, pk0, pk1, pk2, pk3);
    lse_all<<<NSLAB, 256, 0, stream>>>(w0, eb0, w1, eb1, w2, eb2, w3, eb3,
                                       pk0, pk1, pk2, pk3, part);
    reduce_part<<<128, 256, 0, stream>>>(part, sums);
    finalize<<<256, 256, 0, stream>>>(target, projf, sums,
                                      w0, b0, w1, b1, w2, b2, w3, b3, (float*)d_out);
}

// Round 4
// 305.106 us; speedup vs baseline: 1.1225x; 1.0181x over previous
//
#include <hip/hip_runtime.h>
#include <hip/hip_bf16.h>
#include <math.h>

#define NTOK 1024
#define DPROJ 1024
#define PSTRIDE 1376
#define HEADS 20003
#define LOG2E 1.4426950408889634f
#define LN2   0.6931471805599453f
#define WSCALE (4.0f * LOG2E)
#define PSCALE 0.25f

#if __has_builtin(__builtin_amdgcn_exp2f)
#define EXP2(x) __builtin_amdgcn_exp2f(x)
#else
#define EXP2(x) exp2f(x)
#endif

#define MFMA8(a, b, c) __builtin_amdgcn_mfma_f32_16x16x32_fp8_fp8(a, b, c, 0, 0, 0)

typedef __attribute__((ext_vector_type(8))) short bf16x8;
typedef __attribute__((ext_vector_type(4))) float f32x4;
typedef long long i64;
typedef __attribute__((ext_vector_type(2))) long long i64x2;

__device__ __forceinline__ short f2bf(float f) {
    unsigned u = __float_as_uint(f);
    u += 0x7fffu + ((u >> 16) & 1u);
    return (short)(u >> 16);
}
__device__ __forceinline__ unsigned pk4fp8(float a, float b, float c, float d) {
    unsigned v = __builtin_amdgcn_cvt_pk_fp8_f32(a, b, 0, false);
    v = __builtin_amdgcn_cvt_pk_fp8_f32(c, d, v, true);
    return v;
}
__device__ __forceinline__ unsigned char fp8_1(float a) {
    return (unsigned char)(__builtin_amdgcn_cvt_pk_fp8_f32(a, a, 0, false) & 0xff);
}
// w row fragment -> fp8 with WSCALE
__device__ __forceinline__ i64 wfrag(const float* wp) {
    float4 x = *(const float4*)(wp);
    float4 y = *(const float4*)(wp + 4);
    unsigned lo = pk4fp8(x.x * WSCALE, x.y * WSCALE, x.z * WSCALE, x.w * WSCALE);
    unsigned hi = pk4fp8(y.x * WSCALE, y.y * WSCALE, y.z * WSCALE, y.w * WSCALE);
    return (i64)(((unsigned long long)hi << 32) | lo);
}

// block counts for fused lse_all (one slab = 1024-token partials per block)
#define NB0H 313         // head: VT=1, 64 rows/block  (313*64 = 20032 >= 20003)
#define NB1T 157         // t1:   VT=2, 128 rows/block (157*128 = 20096)
#define NB2T 313         // t2:   VT=8, 512 rows/block (313*512 = 160256)
#define NB3T 133         // t3:   VT=8, 512 rows/block (133*512 = 68096)
#define NSLAB (NB0H + NB1T + NB2T + NB3T)   // 916

// padded eb sizes (rows covered by the lse grids)
#define EB0N 20096
#define EB1N 20096
#define EB2N 160256
#define EB3N 68096
#define EBTOT (EB0N + EB1N + EB2N + EB3N)  // 268544 = 1049*256

// ================= prep (+ absorbed memsets + eb tables) ========================
__global__ __launch_bounds__(256) void prep(const float* __restrict__ hidden,
                                            const float* __restrict__ p0,
                                            const float* __restrict__ p1,
                                            const float* __restrict__ p2,
                                            const float* __restrict__ p3,
                                            const float* __restrict__ b0,
                                            const float* __restrict__ b1,
                                            const float* __restrict__ b2,
                                            const float* __restrict__ b3,
                                            short* __restrict__ hbP,
                                            short* __restrict__ pTbP0,
                                            short* __restrict__ pTbP1,
                                            short* __restrict__ pTbP2,
                                            short* __restrict__ pTbP3,
                                            float* __restrict__ sums,
                                            unsigned char* __restrict__ pk3,
                                            float* __restrict__ eb0,
                                            float* __restrict__ eb1,
                                            float* __restrict__ eb2,
                                            float* __restrict__ eb3) {
    __shared__ float tile[64][65];
    int bid = blockIdx.x, tid = threadIdx.x;
    if (bid >= 418) {                       // eb tables: exp2(bias*log2e), 0 on pad rows
        int g = (bid - 418) * 256 + tid;
        if (g < EB0N) {
            eb0[g] = (g < HEADS) ? exp2f(b0[g] * LOG2E) : 0.f;
        } else if (g < EB0N + EB1N) {
            int i = g - EB0N;
            eb1[i] = (i < 20000) ? exp2f(b1[i] * LOG2E) : 0.f;
        } else if (g < EB0N + EB1N + EB2N) {
            int i = g - EB0N - EB1N;
            eb2[i] = (i < 160000) ? exp2f(b2[i] * LOG2E) : 0.f;
        } else if (g < EBTOT) {
            int i = g - EB0N - EB1N - EB2N;
            eb3[i] = (i < 67735) ? exp2f(b3[i] * LOG2E) : 0.f;
        }
        return;
    }
    if (bid == 416) {                       // zero sums (4*1024 floats) for reduce_part atomics
        float4 z = {0.f, 0.f, 0.f, 0.f};
        #pragma unroll
        for (int i = 0; i < 4; ++i) *((float4*)sums + i * 256 + tid) = z;
        return;
    }
    if (bid == 417) {                       // zero pk3 (32768 B, for k-pad)
        int4 z = {0, 0, 0, 0};
        #pragma unroll
        for (int i = 0; i < 8; ++i) *((int4*)pk3 + i * 256 + tid) = z;
        return;
    }
    if (bid < 64) {
        int tt = bid;
        #pragma unroll
        for (int q = 0; q < 8; ++q) {
            int fi = q * 256 + tid;
            int l = fi & 63;
            int row = tt * 16 + (l & 15);
            int kb = (fi >> 6) * 32 + (l >> 4) * 8;
            const float* hp = hidden + row * 1024 + kb;
            float4 x = *(const float4*)hp;
            float4 y = *(const float4*)(hp + 4);
            bf16x8 o;
            o[0]=f2bf(x.x); o[1]=f2bf(x.y); o[2]=f2bf(x.z); o[3]=f2bf(x.w);
            o[4]=f2bf(y.x); o[5]=f2bf(y.y); o[6]=f2bf(y.z); o[7]=f2bf(y.w);
            *(bf16x8*)(hbP + (size_t)tt * 16384 + fi * 8) = o;
        }
        return;
    }
    int lb = bid - 64;
    const float* p; short* dst; int d, kt, jb;
    if (lb < 256)      { p = p0; dst = pTbP0; d = 1024; kt = lb >> 4; jb = lb & 15; }
    else if (lb < 320) { lb -= 256; p = p1; dst = pTbP1; d = 256; kt = lb >> 2; jb = lb & 3; }
    else if (lb < 336) { lb -= 320; p = p2; dst = pTbP2; d = 64;  kt = lb; jb = 0; }
    else               { lb -= 336; p = p3; dst = pTbP3; d = 16;  kt = lb; jb = 0; }
    int k0 = kt * 64, j0 = jb * 64;
    int tx = tid & 63, ty = tid >> 6;
    #pragma unroll
    for (int rr = 0; rr < 16; ++rr) {
        int k = k0 + ty * 16 + rr;
        int j = j0 + tx;
        if (j < d) tile[ty * 16 + rr][tx] = p[k * d + j];
    }
    __syncthreads();
    int ch = tid >> 5;
    int jtl = ch >> 1, ksl = ch & 1;
    int jt = jb * 4 + jtl;
    if (jt * 16 < d) {
        #pragma unroll
        for (int li = 0; li < 2; ++li) {
            int l = (tid & 31) + li * 32;
            int jl = jtl * 16 + (l & 15);
            int kl = ksl * 32 + (l >> 4) * 8;
            bf16x8 o;
            #pragma unroll
            for (int e = 0; e < 8; ++e) o[e] = f2bf(tile[kl + e][jl]);
            *(bf16x8*)(dst + ((size_t)jt * 32 + kt * 2 + ksl) * 512 + l * 8) = o;
        }
    }
}

// ================= proj: bf16 MFMA; projf fp32 exact; pk fp8 scaled =============
// pk layout (d>16, "paired"): per token-tile tt, per 64-k group ksp:
//   byte = tt*(KSp*512) + ksp*1024 + lane*16 + half*8 + e   (half = (k>>5)&1)
//   -> one 16B read per lane yields the i64 B-frags for ks=2*ksp and 2*ksp+1.
// pk3 (d=16) keeps the old unpaired 512B-slice layout.
__global__ __launch_bounds__(256) void proj(const short* __restrict__ hbP,
                                            const short* __restrict__ pTbP0,
                                            const short* __restrict__ pTbP1,
                                            const short* __restrict__ pTbP2,
                                            const short* __restrict__ pTbP3,
                                            float* __restrict__ projf,
                                            unsigned char* __restrict__ pk0,
                                            unsigned char* __restrict__ pk1,
                                            unsigned char* __restrict__ pk2,
                                            unsigned char* __restrict__ pk3) {
    __shared__ float spackf[16][72];
    __shared__ unsigned char sp8[1024];
    int tt = blockIdx.x, jbG = blockIdx.y, tid = threadIdx.x;
    const short* pB; unsigned char* pkc; int d, KSp, coloff, jb;
    if (jbG < 16)      { pB = pTbP0; pkc = pk0; d = 1024; KSp = 32; coloff = 0;    jb = jbG; }
    else if (jbG < 20) { pB = pTbP1; pkc = pk1; d = 256;  KSp = 8;  coloff = 1024; jb = jbG - 16; }
    else if (jbG == 20){ pB = pTbP2; pkc = pk2; d = 64;   KSp = 2;  coloff = 1280; jb = 0; }
    else               { pB = pTbP3; pkc = pk3; d = 16;   KSp = 1;  coloff = 1344; jb = 0; }
    int w = tid >> 6, lane = tid & 63;
    int l16 = lane & 15, quad = lane >> 4;
    int jt = jb * 4 + w;
    if (jt * 16 < d) {
        const short* ap = hbP + ((size_t)tt * 32) * 512 + lane * 8;
        const short* bp = pB  + ((size_t)jt * 32) * 512 + lane * 8;
        f32x4 x0 = {0,0,0,0}, x1 = {0,0,0,0};
        #pragma unroll
        for (int ks = 0; ks < 16; ++ks) {
            bf16x8 a0 = *(const bf16x8*)(ap + ks * 512);
            bf16x8 b0 = *(const bf16x8*)(bp + ks * 512);
            bf16x8 a1 = *(const bf16x8*)(ap + (ks + 16) * 512);
            bf16x8 b1 = *(const bf16x8*)(bp + (ks + 16) * 512);
            x0 = __builtin_amdgcn_mfma_f32_16x16x32_bf16(a0, b0, x0, 0, 0, 0);
            x1 = __builtin_amdgcn_mfma_f32_16x16x32_bf16(a1, b1, x1, 0, 0, 0);
        }
        f32x4 acc = x0 + x1;
        int kk = w * 16 + l16;
        #pragma unroll
        for (int r = 0; r < 4; ++r) {
            int tok = quad * 4 + r;
            spackf[tok][kk] = acc[r];
            int idx;
            if (d > 16) idx = ((kk & 31) >> 3) * 256 + tok * 16 + (kk >> 5) * 8 + (kk & 7);
            else        idx = ((kk & 31) >> 3) * 128 + tok * 8 + (kk & 7);
            sp8[idx] = fp8_1(acc[r] * PSCALE);
        }
    }
    __syncthreads();
    int j0g = jb * 64;
    int dcols = min(64, d - j0g);
    {
        int row = tid >> 4, cb = (tid & 15) * 4;
        if (cb < dcols) {
            float4 v = *(const float4*)&spackf[row][cb];
            *(float4*)&projf[(tt * 16 + row) * PSTRIDE + coloff + j0g + cb] = v;
        }
    }
    {
        int nbytes = 16 * dcols;
        if (tid * 4 < nbytes) {
            unsigned char* gdst = pkc + ((size_t)tt * KSp + (j0g >> 5)) * 512;
            *(unsigned*)(gdst + tid * 4) = *(const unsigned*)(sp8 + tid * 4);
        }
    }
}

// ================= lse =========================================================
__device__ __forceinline__ void stage16k(const unsigned char* g, unsigned char* l,
                                         int wave, int lane) {
    const unsigned char* gs = g + wave * 4096 + lane * 16;
    unsigned char* ls = l + wave * 4096;
    #pragma unroll
    for (int i = 0; i < 4; ++i)
        __builtin_amdgcn_global_load_lds(
            (const __attribute__((address_space(1))) unsigned*)(gs + i * 1024),
            (__attribute__((address_space(3))) unsigned*)(ls + i * 1024), 16, 0, 0);
}

// head: VT=1 (areg = 32 i64, lives in AGPRs), paired b128 reads,
// 3-deep LDS staging ring: stage(tt+2) issued a full compute phase before the
// barrier that drains it -> prefetch latency actually hidden (m97 drain fix).
__device__ __forceinline__ void lse_head(const float* __restrict__ w,
                                         const float* __restrict__ eb,
                                         const unsigned char* __restrict__ pk,
                                         float* __restrict__ part, int bid,
                                         unsigned char (*sbuf)[16384], float* bsum) {
    int tid = threadIdx.x;
    int wave = tid >> 6, lane = tid & 63;
    int quad = lane >> 4, l16 = lane & 15;
    int v0 = bid * 64 + wave * 16;

    for (int i = tid; i < NTOK; i += 256) bsum[i] = 0.f;

    i64 areg[32];
    float ee[4];
    int va = v0 + l16;
    #pragma unroll
    for (int ks = 0; ks < 32; ++ks)
        areg[ks] = (va < HEADS) ? wfrag(w + (long)va * 1024 + ks * 32 + quad * 8) : 0;
    #pragma unroll
    for (int r = 0; r < 4; ++r)
        ee[r] = eb[v0 + quad * 4 + r];   // padded: 0 beyond HEADS

    unsigned char* pA = sbuf[0];   // current compute buffer
    unsigned char* pB = sbuf[1];   // next (already staged)
    unsigned char* pS = sbuf[2];   // stage target (tt+2)
    stage16k(pk, pA, wave, lane);
    stage16k(pk + 16384, pB, wave, lane);
    __syncthreads();
    for (int tt = 0; tt < 64; ++tt) {
        if (tt + 2 < 64) stage16k(pk + (size_t)(tt + 2) * 16384, pS, wave, lane);
        const unsigned char* sb = pA;
        f32x4 x0 = {0,0,0,0}, x1 = x0;
        __builtin_amdgcn_s_setprio(1);
        #pragma unroll
        for (int p = 0; p < 16; ++p) {
            i64x2 b2 = *(const i64x2*)(sb + p * 1024 + lane * 16);
            x0 = MFMA8(areg[2 * p],     b2[0], x0);
            x1 = MFMA8(areg[2 * p + 1], b2[1], x1);
        }
        __builtin_amdgcn_s_setprio(0);
        f32x4 a = x0 + x1;
        float e0 = EXP2(a[0]) * ee[0] + EXP2(a[2]) * ee[2];
        float e1 = EXP2(a[1]) * ee[1] + EXP2(a[3]) * ee[3];
        float e = e0 + e1;
        e += __shfl_xor(e, 16, 64);
        e += __shfl_xor(e, 32, 64);
        if (lane < 16) atomicAdd(&bsum[tt * 16 + lane], e);
        __syncthreads();                 // drains stage(tt+2): issued ~1 phase ago
        unsigned char* t = pA; pA = pB; pB = pS; pS = t;   // rotate ring
    }
    *((float4*)part + tid) = *((const float4*)bsum + tid);
}

// tails: global-direct B with register double-buffer (paired 16B loads for KS>=2).
// Per tt: one clean setprio-wrapped MFMA cluster over all VT, then exp epilogue.
template <int KS, int VT>
__device__ __forceinline__ void lse_tail(const float* __restrict__ w,
                                         const float* __restrict__ eb,
                                         const unsigned char* __restrict__ pk,
                                         float* __restrict__ part,
                                         int V, int D, int bid, float* bsum) {
    int tid = threadIdx.x;
    int wave = tid >> 6, lane = tid & 63;
    int quad = lane >> 4, l16 = lane & 15;
    int v0 = bid * (64 * VT) + wave * (16 * VT);

    for (int i = tid; i < NTOK; i += 256) bsum[i] = 0.f;
    __syncthreads();

    i64 areg[VT][KS];
    float ee[VT][4];
    #pragma unroll
    for (int vt = 0; vt < VT; ++vt) {
        int va = v0 + vt * 16 + l16;
        #pragma unroll
        for (int ks = 0; ks < KS; ++ks) {
            int k = ks * 32 + quad * 8;
            areg[vt][ks] = (va < V && k < D) ? wfrag(w + (long)va * D + k) : 0;
        }
        #pragma unroll
        for (int r = 0; r < 4; ++r)
            ee[vt][r] = eb[v0 + vt * 16 + quad * 4 + r];   // padded: 0 beyond V
    }

    if constexpr (KS >= 2) {
        constexpr int KSP = KS / 2;
        i64x2 bn[KSP], bc[KSP];
        #pragma unroll
        for (int p = 0; p < KSP; ++p)
            bn[p] = *(const i64x2*)(pk + p * 1024 + lane * 16);
        for (int tt = 0; tt < 64; ++tt) {
            #pragma unroll
            for (int p = 0; p < KSP; ++p) bc[p] = bn[p];
            if (tt < 63) {
                const unsigned char* nb = pk + (size_t)(tt + 1) * (KS * 512);
                #pragma unroll
                for (int p = 0; p < KSP; ++p)
                    bn[p] = *(const i64x2*)(nb + p * 1024 + lane * 16);
            }
            f32x4 accs[VT];
            __builtin_amdgcn_s_setprio(1);
            #pragma unroll
            for (int vt = 0; vt < VT; ++vt) {
                if constexpr (KS >= 4) {
                    f32x4 y0 = {0,0,0,0}, y1 = {0,0,0,0};
                    #pragma unroll
                    for (int p = 0; p < KSP; ++p) {
                        y0 = MFMA8(areg[vt][2 * p],     bc[p][0], y0);
                        y1 = MFMA8(areg[vt][2 * p + 1], bc[p][1], y1);
                    }
                    accs[vt] = y0 + y1;
                } else {
                    f32x4 y = {0,0,0,0};
                    y = MFMA8(areg[vt][0], bc[0][0], y);
                    y = MFMA8(areg[vt][1], bc[0][1], y);   // chained: no merge add
                    accs[vt] = y;
                }
            }
            __builtin_amdgcn_s_setprio(0);
            float e0 = 0.f, e1 = 0.f;
            #pragma unroll
            for (int vt = 0; vt < VT; ++vt) {
                e0 += EXP2(accs[vt][0]) * ee[vt][0];
                e1 += EXP2(accs[vt][1]) * ee[vt][1];
                e0 += EXP2(accs[vt][2]) * ee[vt][2];
                e1 += EXP2(accs[vt][3]) * ee[vt][3];
            }
            float e = e0 + e1;
            e += __shfl_xor(e, 16, 64);
            e += __shfl_xor(e, 32, 64);
            if (lane < 16) atomicAdd(&bsum[tt * 16 + lane], e);
        }
    } else {
        i64 bn = *(const i64*)(pk + lane * 8);
        for (int tt = 0; tt < 64; ++tt) {
            i64 bc = bn;
            if (tt < 63) bn = *(const i64*)(pk + (size_t)(tt + 1) * 512 + lane * 8);
            f32x4 accs[VT];
            __builtin_amdgcn_s_setprio(1);
            #pragma unroll
            for (int vt = 0; vt < VT; ++vt) {
                f32x4 y0 = {0,0,0,0};
                accs[vt] = MFMA8(areg[vt][0], bc, y0);
            }
            __builtin_amdgcn_s_setprio(0);
            float e0 = 0.f, e1 = 0.f;
            #pragma unroll
            for (int vt = 0; vt < VT; ++vt) {
                e0 += EXP2(accs[vt][0]) * ee[vt][0];
                e1 += EXP2(accs[vt][1]) * ee[vt][1];
                e0 += EXP2(accs[vt][2]) * ee[vt][2];
                e1 += EXP2(accs[vt][3]) * ee[vt][3];
            }
            float e = e0 + e1;
            e += __shfl_xor(e, 16, 64);
            e += __shfl_xor(e, 32, 64);
            if (lane < 16) atomicAdd(&bsum[tt * 16 + lane], e);
        }
    }
    __syncthreads();
    *((float4*)part + tid) = *((const float4*)bsum + tid);
}

__global__ __launch_bounds__(256, 2) void lse_all(const float* __restrict__ w0, const float* __restrict__ eb0,
                                                  const float* __restrict__ w1, const float* __restrict__ eb1,
                                                  const float* __restrict__ w2, const float* __restrict__ eb2,
                                                  const float* __restrict__ w3, const float* __restrict__ eb3,
                                                  const unsigned char* __restrict__ pk0,
                                                  const unsigned char* __restrict__ pk1,
                                                  const unsigned char* __restrict__ pk2,
                                                  const unsigned char* __restrict__ pk3,
                                                  float* __restrict__ part) {
    __shared__ unsigned char sbuf[3][16384];
    __shared__ float bsum[NTOK];
    int bid = blockIdx.x;
    float* slab = part + (size_t)bid * NTOK;
    if (bid < NB0H) {
        lse_head(w0, eb0, pk0, slab, bid, sbuf, bsum);
    } else if (bid < NB0H + NB1T) {
        lse_tail<8, 2>(w1, eb1, pk1, slab, 20000,  256, bid - NB0H, bsum);
    } else if (bid < NB0H + NB1T + NB2T) {
        lse_tail<2, 8>(w2, eb2, pk2, slab, 160000, 64,  bid - NB0H - NB1T, bsum);
    } else {
        lse_tail<1, 8>(w3, eb3, pk3, slab, 67735,  16,  bid - NB0H - NB1T - NB2T, bsum);
    }
}

// ================= reduce partial slabs -> sums ================================
__global__ __launch_bounds__(256) void reduce_part(const float* __restrict__ part,
                                                   float* __restrict__ sums) {
    // grid: 4 clusters * 4 token-quarters * 8 slab-slices = 128 blocks
    int bid = blockIdx.x;
    int c = bid >> 5, rem = bid & 31, q = rem >> 3, sl = rem & 7;
    const int off[4] = {0, NB0H, NB0H + NB1T, NB0H + NB1T + NB2T};
    const int cnt[4] = {NB0H, NB1T, NB2T, NB3T};
    int tok = q * 256 + threadIdx.x;
    const float* p = part + (size_t)off[c] * NTOK + tok;
    int n = cnt[c];
    float s0 = 0.f, s1 = 0.f, s2 = 0.f, s3 = 0.f;
    int b = sl;
    for (; b + 24 < n; b += 32) {
        s0 += p[(size_t)b * NTOK];
        s1 += p[(size_t)(b + 8) * NTOK];
        s2 += p[(size_t)(b + 16) * NTOK];
        s3 += p[(size_t)(b + 24) * NTOK];
    }
    for (; b < n; b += 8) s0 += p[(size_t)b * NTOK];
    float s = (s0 + s1) + (s2 + s3);
    atomicAdd(&sums[c * NTOK + tok], s);   // 8 atomics/address, sums pre-zeroed in prep
}

// ================= finalize ====================================================
__global__ __launch_bounds__(256) void finalize(const int* __restrict__ target,
                                                const float* __restrict__ projf,
                                                const float* __restrict__ sums,
                                                const float* __restrict__ w0, const float* __restrict__ b0,
                                                const float* __restrict__ w1, const float* __restrict__ b1,
                                                const float* __restrict__ w2, const float* __restrict__ b2,
                                                const float* __restrict__ w3, const float* __restrict__ b3,
                                                float* __restrict__ out) {
    int wave = threadIdx.x >> 6, lane = threadIdx.x & 63;
    int row = blockIdx.x * 4 + wave;
    int t = target[row];
    int c = (t < 20000) ? 0 : (t < 40000) ? 1 : (t < 200000) ? 2 : 3;
    int col0 = (c == 0) ? t : (HEADS - c);
    const float* pr = projf + row * PSTRIDE;

    float s = 0.f;
    for (int k = lane; k < DPROJ; k += 64) s += pr[k] * w0[col0 * DPROJ + k];
    #pragma unroll
    for (int off = 32; off; off >>= 1) s += __shfl_xor(s, off, 64);
    float hl = s + b0[col0];
    float lse0 = __log2f(sums[row]) * LN2;

    float res;
    if (c == 0) {
        res = lse0 - hl;
    } else {
        const float* wc; const float* bc; int d, coloff, l;
        if (c == 1)      { wc = w1; bc = b1; d = 256; coloff = 1024; l = 20000; }
        else if (c == 2) { wc = w2; bc = b2; d = 64;  coloff = 1280; l = 40000; }
        else             { wc = w3; bc = b3; d = 16;  coloff = 1344; l = 200000; }
        int tc = t - l;
        float s2 = 0.f;
        for (int k = lane; k < d; k += 64) s2 += pr[coloff + k] * wc[tc * d + k];
        #pragma unroll
        for (int off = 32; off; off >>= 1) s2 += __shfl_xor(s2, off, 64);
        float tl = s2 + bc[tc];
        float lsec = __log2f(sums[c * NTOK + row]) * LN2;
        res = lse0 - hl + lsec - tl;
    }
    if (lane == 0) out[row] = res;
}

// ================= workspace layout =============================================
// hbP   (short) @ elem 0          : 1,048,576
// pTbP0 (short) @ elem 1,048,576  : 1,048,576
// pTbP1 (short) @ elem 2,097,152  :   262,144
// pTbP2 (short) @ elem 2,359,296  :    65,536
// pTbP3 (short) @ elem 2,424,832  :    16,384
// projf (float) @ byte 4,882,432  : 1,409,024 floats
// pk0..3 (u8)   @ byte 10,518,528 : 1 MB / 256 KB / 64 KB / 32 KB
// sums  (float) @ byte 11,927,552 : 4096 floats           -> ends 11,943,936
// part  (float) @ byte 11,943,936 : 916*1024 floats (3,751,936 B) -> ends 15,695,872
// eb0   (float) @ byte 15,695,872 : 20096  (80,384 B)
// eb1   (float) @ byte 15,776,256 : 20096  (80,384 B)
// eb2   (float) @ byte 15,856,640 : 160256 (641,024 B)
// eb3   (float) @ byte 16,497,664 : 68096  (272,384 B)    -> ends 16,770,048

extern "C" void kernel_launch(void* const* d_in, const int* in_sizes, int n_in,
                              void* d_out, int out_size, void* d_ws, size_t ws_size,
                              hipStream_t stream) {
    const float* hidden = (const float*)d_in[0];
    const int*   target = (const int*)d_in[1];
    const float* w0 = (const float*)d_in[2];
    const float* b0 = (const float*)d_in[3];
    const float* p0 = (const float*)d_in[4];
    const float* w1 = (const float*)d_in[5];
    const float* b1 = (const float*)d_in[6];
    const float* p1 = (const float*)d_in[7];
    const float* w2 = (const float*)d_in[8];
    const float* b2 = (const float*)d_in[9];
    const float* p2 = (const float*)d_in[10];
    const float* w3 = (const float*)d_in[11];
    const float* b3 = (const float*)d_in[12];
    const float* p3 = (const float*)d_in[13];

    short* base = (short*)d_ws;
    short* hbP   = base;
    short* pTbP0 = base + 1048576;
    short* pTbP1 = base + 2097152;
    short* pTbP2 = base + 2359296;
    short* pTbP3 = base + 2424832;
    float* projf = (float*)((char*)d_ws + 4882432);
    unsigned char* pk0 = (unsigned char*)d_ws + 10518528;
    unsigned char* pk1 = pk0 + 1048576;
    unsigned char* pk2 = pk1 + 262144;
    unsigned char* pk3 = pk2 + 65536;
    float* sums  = (float*)((char*)d_ws + 11927552);
    float* part  = (float*)((char*)d_ws + 11943936);
    float* eb0   = (float*)((char*)d_ws + 15695872);
    float* eb1   = (float*)((char*)d_ws + 15776256);
    float* eb2   = (float*)((char*)d_ws + 15856640);
    float* eb3   = (float*)((char*)d_ws + 16497664);

    prep<<<1467, 256, 0, stream>>>(hidden, p0, p1, p2, p3, b0, b1, b2, b3,
                                   hbP, pTbP0, pTbP1, pTbP2, pTbP3, sums, pk3,
                                   eb0, eb1, eb2, eb3);
    proj<<<dim3(64, 22), 256, 0, stream>>>(hbP, pTbP0, pTbP1, pTbP2, pTbP3,
                                           projf, pk0, pk1, pk2, pk3);
    lse_all<<<NSLAB, 256, 0, stream>>>(w0, eb0, w1, eb1, w2, eb2, w3, eb3,
                                       pk0, pk1, pk2, pk3, part);
    reduce_part<<<128, 256, 0, stream>>>(part, sums);
    finalize<<<256, 256, 0, stream>>>(target, projf, sums,
                                      w0, b0, w1, b1, w2, b2, w3, b3, (float*)d_out);
}